// Round 1
// baseline (14658.670 us; speedup 1.0000x reference)
//
#include <hip/hip_runtime.h>
#include <cstdint>

// ---------------------------------------------------------------------------
// 2-layer tanh RNN (B=256,S=2048,D=64,H=256) as a persistent 3-stage pipeline.
// 16 batch-tiles x {A: layer0 rec, B1: pre1 producer, B2: layer1 rec} = 48 WGs.
// Cross-stage handoff through rings in d_ws with agent-scope flags.
// ---------------------------------------------------------------------------

#define S_LEN 2048
#define DIN   64
#define HDIM  256
#define TBLK  512     // 8 waves

typedef __attribute__((ext_vector_type(8))) short bf16x8;
typedef __attribute__((ext_vector_type(4))) float f32x4;

__device__ __forceinline__ short f2bf(float f) {
  unsigned u = __builtin_bit_cast(unsigned, f);
  u += 0x7FFFu + ((u >> 16) & 1u);           // RNE
  return (short)(u >> 16);
}
__device__ __forceinline__ float bf2f(unsigned short h) {
  return __builtin_bit_cast(float, ((unsigned)h) << 16);
}
__device__ __forceinline__ bf16x8 cvt8(f32x4 a, f32x4 b) {
  bf16x8 r;
  r[0]=f2bf(a[0]); r[1]=f2bf(a[1]); r[2]=f2bf(a[2]); r[3]=f2bf(a[3]);
  r[4]=f2bf(b[0]); r[5]=f2bf(b[1]); r[6]=f2bf(b[2]); r[7]=f2bf(b[3]);
  return r;
}
__device__ __forceinline__ bf16x8 load8cvt(const float* p) {
  f32x4 a = *(const f32x4*)p;
  f32x4 b = *(const f32x4*)(p + 4);
  return cvt8(a, b);
}
__device__ __forceinline__ f32x4 mfma16(bf16x8 a, bf16x8 b, f32x4 c) {
  return __builtin_amdgcn_mfma_f32_16x16x32_bf16(a, b, c, 0, 0, 0);
}
__device__ __forceinline__ float fast_tanh(float x) {
  float ax = __builtin_fabsf(x);
  float e  = __expf(-2.f * ax);                       // (0,1]
  float r  = (1.f - e) * __builtin_amdgcn_rcpf(1.f + e);
  return __builtin_copysignf(r, x);
}
__device__ __forceinline__ unsigned ld_acq(unsigned* p) {
  return __hip_atomic_load(p, __ATOMIC_ACQUIRE, __HIP_MEMORY_SCOPE_AGENT);
}
__device__ __forceinline__ unsigned ld_rlx(unsigned* p) {
  return __hip_atomic_load(p, __ATOMIC_RELAXED, __HIP_MEMORY_SCOPE_AGENT);
}
__device__ __forceinline__ void st_rlx(unsigned* p, unsigned v) {
  __hip_atomic_store(p, v, __ATOMIC_RELAXED, __HIP_MEMORY_SCOPE_AGENT);
}
// fragment-major offset: element (hidden k, row m) of a 16x256 tile.
// A wave's A-fragment read is then exactly 16B at kt*1024 + lane*16 (conflict-free).
__device__ __forceinline__ int frag_off(int k, int m) {
  return ((k >> 5) << 10) | (((k >> 3) & 3) << 8) | (m << 4) | ((k & 7) << 1);
}

__global__ void zero_ws_kernel(unsigned* p) {
  p[blockIdx.x * 256 + threadIdx.x] = 0u;   // zeroes 8KB counter region
}

__global__ void __launch_bounds__(TBLK)
rnn_pipeline(const float* __restrict__ x,
             const float* __restrict__ Wih0, const float* __restrict__ Whh0,
             const float* __restrict__ bih0, const float* __restrict__ bhh0,
             const float* __restrict__ Wih1, const float* __restrict__ Whh1,
             const float* __restrict__ bih1, const float* __restrict__ bhh1,
             const float* __restrict__ Wout, const float* __restrict__ bout,
             float* __restrict__ out, char* __restrict__ ws, int W) {
  __shared__ __align__(16) char smem[17408];   // 2x8KB h ping-pong + 1KB scratch

  const int tid  = threadIdx.x;
  const int w    = tid >> 6;      // wave 0..7
  const int l    = tid & 63;
  const int lm   = l & 15;
  const int lq   = l >> 4;        // 0..3
  const int role = blockIdx.x >> 4;   // 0=A,1=B1,2=B2  (role*16+tile => same XCD per tile)
  const int tile = blockIdx.x & 15;

  unsigned* cnt   = (unsigned*)ws;
  unsigned* cntA  = cnt + (size_t)tile * 32;
  unsigned* cntB1 = cnt + 512 + (size_t)tile * 32;
  unsigned* cntB2 = cnt + 1024 + (size_t)tile * 32;
  char* rings    = ws + 65536;
  char* ys_tile  = rings + (size_t)tile * ((size_t)W * 8192);
  char* pre_base = rings + (size_t)16 * (size_t)W * 8192;
  char* pre_tile = pre_base + (size_t)tile * ((size_t)W * 16384);

  if (role == 0) {
    // ================= Role A: layer-0 recurrence + inline x-projection ======
    bf16x8 whh0[2][8], wih0[2][2];
    float bias0[2];
#pragma unroll
    for (int nt = 0; nt < 2; ++nt) {
      int n = ((w * 2 + nt) << 4) + lm;
#pragma unroll
      for (int kt = 0; kt < 8; ++kt)
        whh0[nt][kt] = load8cvt(Whh0 + n * HDIM + kt * 32 + lq * 8);
#pragma unroll
      for (int kt = 0; kt < 2; ++kt)
        wih0[nt][kt] = load8cvt(Wih0 + n * DIN + kt * 32 + lq * 8);
      bias0[nt] = bih0[n] + bhh0[n];
    }
    for (int i = tid; i < 1024; i += TBLK) ((f32x4*)smem)[i] = (f32x4){0.f,0.f,0.f,0.f};
    __syncthreads();

    const float* xrow = x + (size_t)(tile * 16 + lm) * (S_LEN * DIN) + lq * 8;
    unsigned cachedB1 = 0;

    for (int t = 0; t < S_LEN; ++t) {
      const int p = t & 1;
      const float* xp = xrow + t * DIN;
      f32x4 x0 = *(const f32x4*)(xp);
      f32x4 x1 = *(const f32x4*)(xp + 4);
      f32x4 x2 = *(const f32x4*)(xp + 32);
      f32x4 x3 = *(const f32x4*)(xp + 36);

      f32x4 acc0 = {bias0[0], bias0[0], bias0[0], bias0[0]};
      f32x4 acc1 = {bias0[1], bias0[1], bias0[1], bias0[1]};
#pragma unroll
      for (int kt = 0; kt < 8; ++kt) {
        bf16x8 afr = *(const bf16x8*)(smem + p * 8192 + kt * 1024 + (l << 4));
        acc0 = mfma16(afr, whh0[0][kt], acc0);
        acc1 = mfma16(afr, whh0[1][kt], acc1);
      }
      bf16x8 xa0 = cvt8(x0, x1), xa1 = cvt8(x2, x3);
      acc0 = mfma16(xa0, wih0[0][0], acc0);
      acc0 = mfma16(xa1, wih0[0][1], acc0);
      acc1 = mfma16(xa0, wih0[1][0], acc1);
      acc1 = mfma16(xa1, wih0[1][1], acc1);

      // ring anti-dependency guard: B1 must have consumed step t-W
      if (t >= W) {
        while (cachedB1 + (unsigned)W < (unsigned)(t + 1)) {
          cachedB1 = ld_rlx(cntB1); __builtin_amdgcn_s_sleep(2);
        }
      }
      char* ys = ys_tile + (size_t)(t & (W - 1)) * 8192;
#pragma unroll
      for (int nt = 0; nt < 2; ++nt) {
        f32x4 a = nt ? acc1 : acc0;
        int n = ((w * 2 + nt) << 4) + lm;
#pragma unroll
        for (int r = 0; r < 4; ++r) {
          short hv = f2bf(fast_tanh(a[r]));
          int off = frag_off(n, (lq << 2) + r);
          *(short*)(smem + (p ^ 1) * 8192 + off) = hv;   // h for next step
          *(short*)(ys + off) = hv;                      // publish ys0[t]
        }
      }
      __builtin_amdgcn_fence(__ATOMIC_RELEASE, "agent");
      __syncthreads();
      if (tid == 0) st_rlx(cntA, (unsigned)(t + 1));
    }

  } else if (role == 1) {
    // ================= Role B1: pre1[t] = ys0[t] @ W_ih1^T + biases ==========
    bf16x8 wih1[2][8];
    float bias1[2];
#pragma unroll
    for (int nt = 0; nt < 2; ++nt) {
      int n = ((w * 2 + nt) << 4) + lm;
#pragma unroll
      for (int kt = 0; kt < 8; ++kt)
        wih1[nt][kt] = load8cvt(Wih1 + n * HDIM + kt * 32 + lq * 8);
      bias1[nt] = bih1[n] + bhh1[n];
    }
    unsigned cachedA = 0, cachedB2 = 0;
    bf16x8 afA[8], afB[8];
    while (cachedA < 1u) { cachedA = ld_acq(cntA); __builtin_amdgcn_s_sleep(2); }
#pragma unroll
    for (int kt = 0; kt < 8; ++kt)
      afA[kt] = *(const bf16x8*)(ys_tile + kt * 1024 + (l << 4));

    auto b1_step = [&](int t, bf16x8 (&cur)[8], bf16x8 (&nxt)[8]) {
      bool havN = false;
      if (t + 1 < S_LEN) {                         // prefetch ys0[t+1] if ready
        if (cachedA < (unsigned)(t + 2)) cachedA = ld_acq(cntA);
        if (cachedA >= (unsigned)(t + 2)) {
          const char* ns = ys_tile + (size_t)((t + 1) & (W - 1)) * 8192;
#pragma unroll
          for (int kt = 0; kt < 8; ++kt)
            nxt[kt] = *(const bf16x8*)(ns + kt * 1024 + (l << 4));
          havN = true;
        }
      }
      if (t >= W) {                                // B2 must have consumed t-W
        while (cachedB2 + (unsigned)W < (unsigned)(t + 1)) {
          cachedB2 = ld_rlx(cntB2); __builtin_amdgcn_s_sleep(2);
        }
      }
      f32x4 acc0 = {bias1[0], bias1[0], bias1[0], bias1[0]};
      f32x4 acc1 = {bias1[1], bias1[1], bias1[1], bias1[1]};
#pragma unroll
      for (int kt = 0; kt < 8; ++kt) {
        acc0 = mfma16(cur[kt], wih1[0][kt], acc0);
        acc1 = mfma16(cur[kt], wih1[1][kt], acc1);
      }
      char* ps = pre_tile + (size_t)(t & (W - 1)) * 16384 + (l << 4);
      *(f32x4*)(ps + (w * 2 + 0) * 1024) = acc0;   // raw C/D-layout dump
      *(f32x4*)(ps + (w * 2 + 1) * 1024) = acc1;
      __builtin_amdgcn_fence(__ATOMIC_RELEASE, "agent");
      __syncthreads();
      if (tid == 0) st_rlx(cntB1, (unsigned)(t + 1));
      if (!havN && t + 1 < S_LEN) {                // slow path
        while (cachedA < (unsigned)(t + 2)) { cachedA = ld_acq(cntA); __builtin_amdgcn_s_sleep(2); }
        const char* ns = ys_tile + (size_t)((t + 1) & (W - 1)) * 8192;
#pragma unroll
        for (int kt = 0; kt < 8; ++kt)
          nxt[kt] = *(const bf16x8*)(ns + kt * 1024 + (l << 4));
      }
    };
    for (int t = 0; t < S_LEN; t += 2) {
      b1_step(t, afA, afB);
      b1_step(t + 1, afB, afA);
    }

  } else {
    // ================= Role B2: layer-1 recurrence + output ==================
    bf16x8 whh1[2][8];
#pragma unroll
    for (int nt = 0; nt < 2; ++nt) {
      int n = ((w * 2 + nt) << 4) + lm;
#pragma unroll
      for (int kt = 0; kt < 8; ++kt)
        whh1[nt][kt] = load8cvt(Whh1 + n * HDIM + kt * 32 + lq * 8);
    }
    for (int i = tid; i < 1088; i += TBLK) ((f32x4*)smem)[i] = (f32x4){0.f,0.f,0.f,0.f};
    __syncthreads();

    unsigned cached1 = 0;
    f32x4 pA0, pA1, pB0, pB1;
    while (cached1 < 1u) { cached1 = ld_acq(cntB1); __builtin_amdgcn_s_sleep(2); }
    {
      const char* ns = pre_tile + (l << 4);
      pA0 = *(const f32x4*)(ns + (w * 2 + 0) * 1024);
      pA1 = *(const f32x4*)(ns + (w * 2 + 1) * 1024);
    }
    auto b2_step = [&](int t, f32x4 c0, f32x4 c1, f32x4& n0, f32x4& n1) {
      const int p = t & 1;
      bool havN = false;
      f32x4 acc0 = c0, acc1 = c1;          // pre1[t] is the C operand
#pragma unroll
      for (int kt = 0; kt < 8; ++kt) {
        if (kt == 3 && t + 1 < S_LEN) {    // mid-loop prefetch of pre1[t+1]
          if (cached1 < (unsigned)(t + 2)) cached1 = ld_acq(cntB1);
          if (cached1 >= (unsigned)(t + 2)) {
            const char* ns = pre_tile + (size_t)((t + 1) & (W - 1)) * 16384 + (l << 4);
            n0 = *(const f32x4*)(ns + (w * 2 + 0) * 1024);
            n1 = *(const f32x4*)(ns + (w * 2 + 1) * 1024);
            havN = true;
          }
        }
        bf16x8 afr = *(const bf16x8*)(smem + p * 8192 + kt * 1024 + (l << 4));
        acc0 = mfma16(afr, whh1[0][kt], acc0);
        acc1 = mfma16(afr, whh1[1][kt], acc1);
      }
#pragma unroll
      for (int nt = 0; nt < 2; ++nt) {
        f32x4 a = nt ? acc1 : acc0;
        int n = ((w * 2 + nt) << 4) + lm;
#pragma unroll
        for (int r = 0; r < 4; ++r) {
          short hv = f2bf(fast_tanh(a[r]));
          *(short*)(smem + (p ^ 1) * 8192 + frag_off(n, (lq << 2) + r)) = hv;
        }
      }
      __syncthreads();
      if (tid == 0) st_rlx(cntB2, (unsigned)(t + 1));   // loads done (barrier drained)
      if (!havN && t + 1 < S_LEN) {
        while (cached1 < (unsigned)(t + 2)) { cached1 = ld_acq(cntB1); __builtin_amdgcn_s_sleep(2); }
        const char* ns = pre_tile + (size_t)((t + 1) & (W - 1)) * 16384 + (l << 4);
        n0 = *(const f32x4*)(ns + (w * 2 + 0) * 1024);
        n1 = *(const f32x4*)(ns + (w * 2 + 1) * 1024);
      }
    };
    for (int t = 0; t < S_LEN; t += 2) {
      b2_step(t, pA0, pA1, pB0, pB1);
      b2_step(t + 1, pB0, pB1, pA0, pA1);
    }
    // ---- epilogue: out = sigmoid(h1_last @ W_out^T + b_out); h1 in buf 0 ----
    if (tid < 256) {
      int m = tid >> 4, j = tid & 15;
      float s = 0.f;
#pragma unroll
      for (int kk = 0; kk < 16; ++kk) {
        int k = j * 16 + kk;
        s += bf2f(*(unsigned short*)(smem + frag_off(k, m))) * Wout[k];
      }
      *(float*)(smem + 16384 + ((m << 4) + j) * 4) = s;
    }
    __syncthreads();
    if (tid < 16) {
      float s = 0.f;
#pragma unroll
      for (int j = 0; j < 16; ++j) s += *(float*)(smem + 16384 + ((tid << 4) + j) * 4);
      s += bout[0];
      out[(tile << 4) + tid] = 1.f / (1.f + __expf(-s));
    }
  }
}

extern "C" void kernel_launch(void* const* d_in, const int* in_sizes, int n_in,
                              void* d_out, int out_size, void* d_ws, size_t ws_size,
                              hipStream_t stream) {
  (void)in_sizes; (void)n_in; (void)out_size;
  const float* x    = (const float*)d_in[0];
  const float* Wih0 = (const float*)d_in[1];
  const float* Whh0 = (const float*)d_in[2];
  const float* bih0 = (const float*)d_in[3];
  const float* bhh0 = (const float*)d_in[4];
  const float* Wih1 = (const float*)d_in[5];
  const float* Whh1 = (const float*)d_in[6];
  const float* bih1 = (const float*)d_in[7];
  const float* bhh1 = (const float*)d_in[8];
  const float* Wout = (const float*)d_in[9];
  const float* bout = (const float*)d_in[10];

  // ring depth: 64KB counters + W*(16*8KB ys0 + 16*16KB pre1); shrink to fit ws
  int W = 32;
  while (W > 2 && (size_t)65536 + (size_t)W * 393216u > ws_size) W >>= 1;

  zero_ws_kernel<<<dim3(8), dim3(256), 0, stream>>>((unsigned*)d_ws);
  rnn_pipeline<<<dim3(48), dim3(TBLK), 0, stream>>>(
      x, Wih0, Whh0, bih0, bhh0, Wih1, Whh1, bih1, bhh1, Wout, bout,
      (float*)d_out, (char*)d_ws, W);
}

// Round 2
// 5246.865 us; speedup vs baseline: 2.7938x; 2.7938x over previous
//
#include <hip/hip_runtime.h>
#include <cstdint>

// ---------------------------------------------------------------------------
// 2-layer tanh RNN (B=256,S=2048,D=64,H=256), fully fused: one persistent WG
// per 16-row batch tile (16 WGs x 512 thr). Both layers per step in a single
// block; h-state ping-pongs in LDS; weights register-resident; zero cross-WG
// communication (R1 showed per-step agent fences cost ~7us/step).
// ---------------------------------------------------------------------------

#define S_LEN 2048
#define DIN   64
#define HDIM  256
#define TBLK  512     // 8 waves

typedef __attribute__((ext_vector_type(8))) short bf16x8;
typedef __attribute__((ext_vector_type(4))) float f32x4;

__device__ __forceinline__ short f2bf(float f) {
  unsigned u = __builtin_bit_cast(unsigned, f);
  u += 0x7FFFu + ((u >> 16) & 1u);           // RNE
  return (short)(u >> 16);
}
__device__ __forceinline__ float bf2f(unsigned short h) {
  return __builtin_bit_cast(float, ((unsigned)h) << 16);
}
__device__ __forceinline__ bf16x8 cvt8(f32x4 a, f32x4 b) {
  bf16x8 r;
  r[0]=f2bf(a[0]); r[1]=f2bf(a[1]); r[2]=f2bf(a[2]); r[3]=f2bf(a[3]);
  r[4]=f2bf(b[0]); r[5]=f2bf(b[1]); r[6]=f2bf(b[2]); r[7]=f2bf(b[3]);
  return r;
}
__device__ __forceinline__ bf16x8 load8cvt(const float* p) {
  f32x4 a = *(const f32x4*)p;
  f32x4 b = *(const f32x4*)(p + 4);
  return cvt8(a, b);
}
__device__ __forceinline__ f32x4 mfma16(bf16x8 a, bf16x8 b, f32x4 c) {
  return __builtin_amdgcn_mfma_f32_16x16x32_bf16(a, b, c, 0, 0, 0);
}
__device__ __forceinline__ float fast_tanh(float x) {
  float ax = __builtin_fabsf(x);
  float e  = __expf(-2.f * ax);                       // (0,1]
  float r  = (1.f - e) * __builtin_amdgcn_rcpf(1.f + e);
  return __builtin_copysignf(r, x);
}
// fragment-major offset: element (k, row m) of a 16x256 bf16 tile.
// A wave's A-fragment read is exactly 16B at kt*1024 + lane*16 (contiguous 1KB).
__device__ __forceinline__ int frag_off(int k, int m) {
  return ((k >> 5) << 10) | (((k >> 3) & 3) << 8) | (m << 4) | ((k & 7) << 1);
}

__global__ void __launch_bounds__(TBLK, 2)
rnn_fused(const float* __restrict__ x,
          const float* __restrict__ Wih0, const float* __restrict__ Whh0,
          const float* __restrict__ bih0, const float* __restrict__ bhh0,
          const float* __restrict__ Wih1, const float* __restrict__ Whh1,
          const float* __restrict__ bih1, const float* __restrict__ bhh1,
          const float* __restrict__ Wout, const float* __restrict__ bout,
          float* __restrict__ out) {
  // [h0 ping 8K][h0 pong 8K][h1 ping 8K][h1 pong 8K][xs0 2K][xs1 2K][ep 1K]
  __shared__ __align__(16) char smem[38912];
  char* const h0b0 = smem;
  char* const h0b1 = smem + 8192;
  char* const h1b0 = smem + 16384;
  char* const h1b1 = smem + 24576;
  char* const xsb0 = smem + 32768;
  char* const xsb1 = smem + 34816;
  float* const ep  = (float*)(smem + 36864);

  const int tid  = threadIdx.x;
  const int w    = tid >> 6;      // wave 0..7
  const int l    = tid & 63;
  const int lm   = l & 15;
  const int lq   = l >> 4;        // 0..3
  const int tile = blockIdx.x;    // 0..15

  // ---- register-resident weight B-fragments (per wave: 2 n-tiles) ----------
  bf16x8 whh0[2][8], wih0[2][2], wih1[2][8], whh1[2][8];
  float bias0[2], bias1[2];
#pragma unroll
  for (int nt = 0; nt < 2; ++nt) {
    int n = ((w * 2 + nt) << 4) + lm;
#pragma unroll
    for (int kt = 0; kt < 8; ++kt) {
      whh0[nt][kt] = load8cvt(Whh0 + n * HDIM + kt * 32 + lq * 8);
      wih1[nt][kt] = load8cvt(Wih1 + n * HDIM + kt * 32 + lq * 8);
      whh1[nt][kt] = load8cvt(Whh1 + n * HDIM + kt * 32 + lq * 8);
    }
#pragma unroll
    for (int kt = 0; kt < 2; ++kt)
      wih0[nt][kt] = load8cvt(Wih0 + n * DIN + kt * 32 + lq * 8);
    bias0[nt] = bih0[n] + bhh0[n];
    bias1[nt] = bih1[n] + bhh1[n];
  }

  // ---- zero initial h0/h1 state, stage x[0] --------------------------------
  ((f32x4*)h0b0)[tid] = (f32x4){0.f, 0.f, 0.f, 0.f};   // 512*16B = 8KB
  ((f32x4*)h1b0)[tid] = (f32x4){0.f, 0.f, 0.f, 0.f};
  const float* xrow = x + (size_t)(tile * 16 + lm) * (S_LEN * DIN);
  if (w < 2) {
    const float* xp = xrow + w * 32 + lq * 8;          // t = 0
    *(bf16x8*)(xsb0 + w * 1024 + (l << 4)) = load8cvt(xp);
  }
  __syncthreads();

  for (int t = 0; t < S_LEN; ++t) {
    const int p = t & 1;
    char* const h0r = p ? h0b1 : h0b0;   // h0[t-1]
    char* const h0w = p ? h0b0 : h0b1;   // h0[t]  (= ys0[t])
    char* const h1r = p ? h1b1 : h1b0;   // h1[t-1]
    char* const h1w = p ? h1b0 : h1b1;   // h1[t]
    char* const xsr = p ? xsb1 : xsb0;   // x[t]
    char* const xsw = p ? xsb0 : xsb1;   // x[t+1]

    // prefetch next x (waves 0,1 only; hidden under layer-0 MFMAs)
    f32x4 xl0, xl1;
    const bool hx = (w < 2) && (t + 1 < S_LEN);
    if (hx) {
      const float* xp = xrow + (t + 1) * DIN + w * 32 + lq * 8;
      xl0 = *(const f32x4*)xp;
      xl1 = *(const f32x4*)(xp + 4);
    }

    // ---------------- layer 0: h0[t] = tanh(x W_ih0^T + h0 W_hh0^T + b) -----
    f32x4 a0 = {bias0[0], bias0[0], bias0[0], bias0[0]};
    f32x4 a1 = {bias0[1], bias0[1], bias0[1], bias0[1]};
#pragma unroll
    for (int kt = 0; kt < 8; ++kt) {
      bf16x8 afr = *(const bf16x8*)(h0r + kt * 1024 + (l << 4));
      a0 = mfma16(afr, whh0[0][kt], a0);
      a1 = mfma16(afr, whh0[1][kt], a1);
    }
    {
      bf16x8 xa0 = *(const bf16x8*)(xsr + (l << 4));
      bf16x8 xa1 = *(const bf16x8*)(xsr + 1024 + (l << 4));
      a0 = mfma16(xa0, wih0[0][0], a0);
      a0 = mfma16(xa1, wih0[0][1], a0);
      a1 = mfma16(xa0, wih0[1][0], a1);
      a1 = mfma16(xa1, wih0[1][1], a1);
    }
    if (hx) *(bf16x8*)(xsw + w * 1024 + (l << 4)) = cvt8(xl0, xl1);
#pragma unroll
    for (int nt = 0; nt < 2; ++nt) {
      f32x4 a = nt ? a1 : a0;
      int n = ((w * 2 + nt) << 4) + lm;
#pragma unroll
      for (int r = 0; r < 4; ++r)
        *(short*)(h0w + frag_off(n, (lq << 2) + r)) = f2bf(fast_tanh(a[r]));
    }
    __syncthreads();

    // ---------------- layer 1: h1[t] = tanh(ys0 W_ih1^T + h1 W_hh1^T + b) ---
    f32x4 c0 = {bias1[0], bias1[0], bias1[0], bias1[0]};
    f32x4 c1 = {bias1[1], bias1[1], bias1[1], bias1[1]};
#pragma unroll
    for (int kt = 0; kt < 8; ++kt) {
      bf16x8 yfr = *(const bf16x8*)(h0w + kt * 1024 + (l << 4));
      c0 = mfma16(yfr, wih1[0][kt], c0);
      c1 = mfma16(yfr, wih1[1][kt], c1);
    }
#pragma unroll
    for (int kt = 0; kt < 8; ++kt) {
      bf16x8 hfr = *(const bf16x8*)(h1r + kt * 1024 + (l << 4));
      c0 = mfma16(hfr, whh1[0][kt], c0);
      c1 = mfma16(hfr, whh1[1][kt], c1);
    }
#pragma unroll
    for (int nt = 0; nt < 2; ++nt) {
      f32x4 c = nt ? c1 : c0;
      int n = ((w * 2 + nt) << 4) + lm;
#pragma unroll
      for (int r = 0; r < 4; ++r)
        *(short*)(h1w + frag_off(n, (lq << 2) + r)) = f2bf(fast_tanh(c[r]));
    }
    __syncthreads();
  }

  // ---- epilogue: out = sigmoid(h1_last @ W_out^T + b_out); h1 in h1b0 ------
  if (tid < 256) {
    int m = tid >> 4, j = tid & 15;
    float s = 0.f;
#pragma unroll
    for (int kk = 0; kk < 16; ++kk) {
      int k = j * 16 + kk;
      s += bf2f(*(unsigned short*)(h1b0 + frag_off(k, m))) * Wout[k];
    }
    ep[(m << 4) + j] = s;
  }
  __syncthreads();
  if (tid < 16) {
    float s = 0.f;
#pragma unroll
    for (int j = 0; j < 16; ++j) s += ep[(tid << 4) + j];
    s += bout[0];
    out[(tile << 4) + tid] = 1.f / (1.f + __expf(-s));
  }
}

extern "C" void kernel_launch(void* const* d_in, const int* in_sizes, int n_in,
                              void* d_out, int out_size, void* d_ws, size_t ws_size,
                              hipStream_t stream) {
  (void)in_sizes; (void)n_in; (void)out_size; (void)d_ws; (void)ws_size;
  const float* x    = (const float*)d_in[0];
  const float* Wih0 = (const float*)d_in[1];
  const float* Whh0 = (const float*)d_in[2];
  const float* bih0 = (const float*)d_in[3];
  const float* bhh0 = (const float*)d_in[4];
  const float* Wih1 = (const float*)d_in[5];
  const float* Whh1 = (const float*)d_in[6];
  const float* bih1 = (const float*)d_in[7];
  const float* bhh1 = (const float*)d_in[8];
  const float* Wout = (const float*)d_in[9];
  const float* bout = (const float*)d_in[10];

  rnn_fused<<<dim3(16), dim3(TBLK), 0, stream>>>(
      x, Wih0, Whh0, bih0, bhh0, Wih1, Whh1, bih1, bhh1, Wout, bout,
      (float*)d_out);
}